// Round 12
// baseline (1277.182 us; speedup 1.0000x reference)
//
#include <hip/hip_runtime.h>
#include <hip/hip_bf16.h>
#include <math.h>

#define B 4096
#define S 32
#define D 256
#define V 50257
#define N_ALIVE 100
#define K_PAD 128          // K=100 zero-padded to 128 (4 x mfma K=32)
#define V_PAD 50432        // 197 * 256
#define NXT   (V_PAD / 256)  // 197 x-tiles

typedef __attribute__((ext_vector_type(8))) short short8;   // 8 bf16 (4 VGPRs)
typedef __attribute__((ext_vector_type(4))) float float4v;  // 4 fp32 (native vec)

__device__ __forceinline__ short f2bf(float f) {
    __hip_bfloat16 h = __float2bfloat16(f);
    return *reinterpret_cast<short*>(&h);
}

// LDS-only barrier: orders ds_write->ds_read across waves WITHOUT draining
// outstanding global stores (unlike __syncthreads, which emits vmcnt(0)).
__device__ __forceinline__ void lds_barrier() {
    asm volatile("s_waitcnt lgkmcnt(0)" ::: "memory");
    __builtin_amdgcn_s_barrier();
}

// ---------------------------------------------------------------------------
// Kernel A v3 (unchanged).  Measured R14: 54 us.
// ---------------------------------------------------------------------------
__global__ __launch_bounds__(256) void ctx_act_kernel(
    const int*   __restrict__ token_ids,   // [B,S]
    const float* __restrict__ te,          // [V,D]
    const float* __restrict__ pe,          // [S,D]
    const float* __restrict__ q,           // [D]
    const float* __restrict__ pos,         // [N,D]
    __hip_bfloat16* __restrict__ A)        // [B, K_PAD]
{
    __shared__ int   s_ids[S];
    __shared__ float s_scores[S];
    __shared__ float s_w[S];
    __shared__ __align__(16) float s_part[4][D];   // 4 KB per-wave partials
    __shared__ __align__(16) float s_ctx[D];
    __shared__ float s_red[128];
    __shared__ float s_total;

    const int b    = blockIdx.x;
    const int tid  = threadIdx.x;
    const int lane = tid & 63;
    const int wave = tid >> 6;

    if (tid < S) s_ids[tid] = token_ids[b * S + tid];
    __syncthreads();

    // ---- phase 1: load embeds (kept in regs) + attention scores ----
    const float4 qv = *(const float4*)(q + lane * 4);
    float4 e4[8];
    #pragma unroll
    for (int j = 0; j < 8; ++j) {
        const int s = wave * 8 + j;
        const float4 t4 = *(const float4*)(te + (size_t)s_ids[s] * D + lane * 4);
        const float4 p4 = *(const float4*)(pe + (size_t)s * D + lane * 4);
        e4[j].x = t4.x + p4.x; e4[j].y = t4.y + p4.y;
        e4[j].z = t4.z + p4.z; e4[j].w = t4.w + p4.w;
        float p = e4[j].x * qv.x + e4[j].y * qv.y + e4[j].z * qv.z + e4[j].w * qv.w;
        #pragma unroll
        for (int m = 32; m >= 1; m >>= 1) p += __shfl_xor(p, m);
        if (lane == 0) s_scores[s] = p * 0.0625f;   // 1/sqrt(256)
    }
    __syncthreads();

    // ---- phase 2: softmax over S=32 (first 32 lanes of wave 0) ----
    if (tid < 32) {
        const float sc = s_scores[tid];
        float m = sc;
        #pragma unroll
        for (int k = 16; k >= 1; k >>= 1) m = fmaxf(m, __shfl_xor(m, k));
        const float e = expf(sc - m);
        float tot = e;
        #pragma unroll
        for (int k = 16; k >= 1; k >>= 1) tot += __shfl_xor(tot, k);
        s_w[tid] = e / tot;
    }
    __syncthreads();

    // ---- phase 3: per-wave partial context, pure register FMA ----
    {
        float4 c4 = {0.f, 0.f, 0.f, 0.f};
        #pragma unroll
        for (int j = 0; j < 8; ++j) {
            const float w = s_w[wave * 8 + j];
            c4.x = fmaf(w, e4[j].x, c4.x);
            c4.y = fmaf(w, e4[j].y, c4.y);
            c4.z = fmaf(w, e4[j].z, c4.z);
            c4.w = fmaf(w, e4[j].w, c4.w);
        }
        *(float4*)&s_part[wave][lane * 4] = c4;
    }
    __syncthreads();

    // ---- phase 4: cross-wave reduce -> s_ctx (thread owns d = tid) ----
    s_ctx[tid] = s_part[0][tid] + s_part[1][tid] + s_part[2][tid] + s_part[3][tid];
    __syncthreads();

    // ---- phase 5: RBF activations: thread n = tid (n < 100) ----
    float a = 0.f;
    if (tid < N_ALIVE) {
        const float4* p4 = (const float4*)(pos + (size_t)tid * D);
        const float4* c4 = (const float4*)s_ctx;
        float d2 = 0.f;
        #pragma unroll 8
        for (int dd = 0; dd < D / 4; ++dd) {
            const float4 cv = c4[dd];
            const float4 pv = p4[dd];
            const float dx = cv.x - pv.x;
            const float dy = cv.y - pv.y;
            const float dz = cv.z - pv.z;
            const float dw = cv.w - pv.w;
            d2 += dx * dx + dy * dy + dz * dz + dw * dw;
        }
        a = expf(-2.0f * d2);   // exp(-d2 / (2 * 0.5^2))
    }
    if (tid < 128) s_red[tid] = (tid < N_ALIVE) ? a : 0.f;
    __syncthreads();
    if (tid < 64) s_red[tid] += s_red[tid + 64];
    __syncthreads();
    if (tid < 64) {
        float v = s_red[tid];
        #pragma unroll
        for (int k = 32; k >= 1; k >>= 1) v += __shfl_xor(v, k);
        if (tid == 0) s_total = v;
    }
    __syncthreads();
    if (tid < K_PAD) {
        const float val = (tid < N_ALIVE) ? (a / (s_total + 1e-8f)) : 0.f;
        A[(size_t)b * K_PAD + tid] = __float2bfloat16(val);
    }
}

// ---------------------------------------------------------------------------
// Transpose/convert: Wt[v][k] = bf16(W[k][v]), zero-padded.  (unchanged)
// ---------------------------------------------------------------------------
__global__ __launch_bounds__(256) void transpose_w(
    const float* __restrict__ W,            // [N_ALIVE, V]
    __hip_bfloat16* __restrict__ Wt)        // [V_PAD, K_PAD]
{
    const int v  = blockIdx.x * 256 + threadIdx.x;
    const int k0 = blockIdx.y * 16;
    short8 p0, p1;
    #pragma unroll
    for (int kk = 0; kk < 8; ++kk) {
        const int k = k0 + kk;
        p0[kk] = f2bf((v < V && k < N_ALIVE) ? W[(size_t)k * V + v] : 0.f);
    }
    #pragma unroll
    for (int kk = 0; kk < 8; ++kk) {
        const int k = k0 + 8 + kk;
        p1[kk] = f2bf((v < V && k < N_ALIVE) ? W[(size_t)k * V + v] : 0.f);
    }
    short* dst = (short*)Wt + (size_t)v * K_PAD + k0;
    *(short8*)dst       = p0;
    *(short8*)(dst + 8) = p1;
}

#define SO_LD 260   // floats per staged row (256 + 4 pad), 16B-aligned stride

// ---------------------------------------------------------------------------
// Kernel B v3 (R21): ROW-OWNING gemm — the R19 probe's store pattern
// (174.5 us pure-store vs 244.7 scattered).  256 blocks x 16 batch rows;
// loop 197 x-tiles left->right = 16 sequential write streams per block.
//   - Act fragments hoisted for BLOCK lifetime (16 rows fixed, 16 VGPR).
//   - Wt streamed per x-tile, double-buffered in regs (cur/nxt, 128 VGPR):
//     next tile's 16 loads issue before this tile's MFMA+stores.
//   - Same MFMA mapping + staged 1-KB epilogue + LDS-only barriers as v2.
// Predicted: gemm ~190-210 us (probe + ~15-30 compute), total ~945-975.
// ---------------------------------------------------------------------------
__global__ __launch_bounds__(256) void gemm_mfma_v3(
    const __hip_bfloat16* __restrict__ Act,  // [B, K_PAD]
    const __hip_bfloat16* __restrict__ Wt,   // [V_PAD, K_PAD]
    float* __restrict__ out)                 // [B, V]
{
    __shared__ __align__(16) float s_out[16 * SO_LD];   // 16.6 KB block tile

    const int tid  = threadIdx.x;
    const int lane = tid & 63;
    const int wave = tid >> 6;
    const int quad = lane >> 4;
    const int l16  = lane & 15;
    const int b0   = blockIdx.x * 16;          // this block's 16 batch rows

    // ---- Act fragments: block lifetime (b-rows fixed) ----
    const short* actp = (const short*)Act + (size_t)(b0 + l16) * K_PAD + quad * 8;
    short8 bfr[4];
    #pragma unroll
    for (int ks = 0; ks < 4; ++ks) bfr[ks] = *(const short8*)(actp + ks * 32);

    // ---- Wt stream base: row (wave*64 + mt*16 + l16), col quad*8 + ks*32 ----
    const short* wtcol = (const short*)Wt + (size_t)(wave * 64 + l16) * K_PAD + quad * 8;

    short8 cur[4][4], nxt[4][4];
    #pragma unroll
    for (int mt = 0; mt < 4; ++mt) {
        #pragma unroll
        for (int ks = 0; ks < 4; ++ks)
            cur[mt][ks] = *(const short8*)(wtcol + (size_t)(mt * 16) * K_PAD + ks * 32);
    }

    for (int xt = 0; xt < NXT; ++xt) {
        const int x0 = xt * 256;
        const bool full_x = (x0 + 256 <= V);

        // ---- prefetch next x-tile's Wt frags (clamped dup on last) ----
        const int xp = (xt + 1 < NXT) ? xt + 1 : xt;
        const short* wp = wtcol + (size_t)xp * 256 * K_PAD;
        #pragma unroll
        for (int mt = 0; mt < 4; ++mt) {
            #pragma unroll
            for (int ks = 0; ks < 4; ++ks)
                nxt[mt][ks] = *(const short8*)(wp + (size_t)(mt * 16) * K_PAD + ks * 32);
        }

        // ---- MFMA: acc[reg] = C[b=l16][v = wave*64 + mt*16 + quad*4 + reg] ----
        #pragma unroll
        for (int mt = 0; mt < 4; ++mt) {
            float4v acc = {0.f, 0.f, 0.f, 0.f};
            #pragma unroll
            for (int ks = 0; ks < 4; ++ks)
                acc = __builtin_amdgcn_mfma_f32_16x16x32_bf16(cur[mt][ks], bfr[ks], acc, 0, 0, 0);
            *(float4v*)(s_out + l16 * SO_LD + wave * 64 + mt * 16 + quad * 4) = acc;
        }

        lds_barrier();   // ds_writes visible; global stores keep flying

        // ---- each wave stores 4 rows: 1 KB contiguous append per row ----
        #pragma unroll
        for (int p = 0; p < 4; ++p) {
            const int row = wave * 4 + p;          // 0..15 (b_local)
            float* orow = out + (size_t)(b0 + row) * V + x0;
            const float* srow = s_out + row * SO_LD;
            if (full_x) {
                *(float4v*)(orow + lane * 4) = *(const float4v*)(srow + lane * 4);
            } else {
                #pragma unroll
                for (int i = 0; i < 4; ++i) {
                    const int c = lane * 4 + i;
                    if (x0 + c < V) orow[c] = srow[c];
                }
            }
        }

        lds_barrier();   // ds_reads done before next overwrite

        #pragma unroll
        for (int mt = 0; mt < 4; ++mt)
            #pragma unroll
            for (int ks = 0; ks < 4; ++ks) cur[mt][ks] = nxt[mt][ks];
    }
}

// ---------------------------------------------------------------------------
// Fallback (ws too small for Wt): fp32 VALU, TB=16 rows in VGPRs.
// ---------------------------------------------------------------------------
__global__ __launch_bounds__(256) void logits_fallback(
    const __hip_bfloat16* __restrict__ A,   // [B, K_PAD]
    const float* __restrict__ W,            // [N_ALIVE, V]
    float* __restrict__ out)                // [B, V]
{
    const int v  = blockIdx.x * 256 + threadIdx.x;
    const int b0 = blockIdx.y * 16;
    const bool valid = (v < V);

    float acc[16];
    #pragma unroll
    for (int i = 0; i < 16; ++i) acc[i] = 0.f;

    for (int k = 0; k < N_ALIVE; ++k) {
        const float w = valid ? W[(size_t)k * V + v] : 0.f;
        #pragma unroll
        for (int i = 0; i < 16; ++i) {
            const float a = __bfloat162float(A[(size_t)(b0 + i) * K_PAD + k]);
            acc[i] = fmaf(a, w, acc[i]);
        }
    }
    if (valid) {
        #pragma unroll
        for (int i = 0; i < 16; ++i)
            out[(size_t)(b0 + i) * V + v] = acc[i];
    }
}

// ---------------------------------------------------------------------------
extern "C" void kernel_launch(void* const* d_in, const int* in_sizes, int n_in,
                              void* d_out, int out_size, void* d_ws, size_t ws_size,
                              hipStream_t stream) {
    const int*   token_ids = (const int*)d_in[0];
    const float* te        = (const float*)d_in[1];
    const float* pe        = (const float*)d_in[2];
    const float* q         = (const float*)d_in[3];
    const float* pos       = (const float*)d_in[4];
    const float* W         = (const float*)d_in[5];
    float*       out       = (float*)d_out;

    __hip_bfloat16* Abf = (__hip_bfloat16*)d_ws;                  // 1 MiB
    const size_t offW   = (size_t)B * K_PAD * sizeof(__hip_bfloat16);
    __hip_bfloat16* Wt  = (__hip_bfloat16*)((char*)d_ws + offW);  // ~12.9 MB
    const size_t need   = offW + (size_t)V_PAD * K_PAD * sizeof(__hip_bfloat16);

    ctx_act_kernel<<<dim3(B), dim3(256), 0, stream>>>(token_ids, te, pe, q, pos, Abf);

    if (ws_size >= need) {
        transpose_w<<<dim3(V_PAD / 256, 8), dim3(256), 0, stream>>>(W, Wt);
        gemm_mfma_v3<<<dim3(B / 16), dim3(256), 0, stream>>>(Abf, Wt, out);
    } else {
        logits_fallback<<<dim3((V + 255) / 256, B / 16), dim3(256), 0, stream>>>(Abf, W, out);
    }
}

// Round 13
// 1257.390 us; speedup vs baseline: 1.0157x; 1.0157x over previous
//
#include <hip/hip_runtime.h>
#include <hip/hip_bf16.h>
#include <math.h>

#define B 4096
#define S 32
#define D 256
#define V 50257
#define N_ALIVE 100
#define K_PAD 128          // K=100 zero-padded to 128 (4 x mfma K=32)
#define V_PAD 50432        // 197 * 256
#define NXT   (V_PAD / 256)  // 197 x-tiles

typedef __attribute__((ext_vector_type(8))) short short8;   // 8 bf16 (4 VGPRs)
typedef __attribute__((ext_vector_type(4))) float float4v;  // 4 fp32 (native vec)

__device__ __forceinline__ short f2bf(float f) {
    __hip_bfloat16 h = __float2bfloat16(f);
    return *reinterpret_cast<short*>(&h);
}

// LDS-only barrier: orders ds_write->ds_read across waves WITHOUT draining
// outstanding global stores (unlike __syncthreads, which emits vmcnt(0)).
__device__ __forceinline__ void lds_barrier() {
    asm volatile("s_waitcnt lgkmcnt(0)" ::: "memory");
    __builtin_amdgcn_s_barrier();
}

// ---------------------------------------------------------------------------
// Kernel A v3 (unchanged).  Measured R14: 54 us.
// ---------------------------------------------------------------------------
__global__ __launch_bounds__(256) void ctx_act_kernel(
    const int*   __restrict__ token_ids,   // [B,S]
    const float* __restrict__ te,          // [V,D]
    const float* __restrict__ pe,          // [S,D]
    const float* __restrict__ q,           // [D]
    const float* __restrict__ pos,         // [N,D]
    __hip_bfloat16* __restrict__ A)        // [B, K_PAD]
{
    __shared__ int   s_ids[S];
    __shared__ float s_scores[S];
    __shared__ float s_w[S];
    __shared__ __align__(16) float s_part[4][D];   // 4 KB per-wave partials
    __shared__ __align__(16) float s_ctx[D];
    __shared__ float s_red[128];
    __shared__ float s_total;

    const int b    = blockIdx.x;
    const int tid  = threadIdx.x;
    const int lane = tid & 63;
    const int wave = tid >> 6;

    if (tid < S) s_ids[tid] = token_ids[b * S + tid];
    __syncthreads();

    // ---- phase 1: load embeds (kept in regs) + attention scores ----
    const float4 qv = *(const float4*)(q + lane * 4);
    float4 e4[8];
    #pragma unroll
    for (int j = 0; j < 8; ++j) {
        const int s = wave * 8 + j;
        const float4 t4 = *(const float4*)(te + (size_t)s_ids[s] * D + lane * 4);
        const float4 p4 = *(const float4*)(pe + (size_t)s * D + lane * 4);
        e4[j].x = t4.x + p4.x; e4[j].y = t4.y + p4.y;
        e4[j].z = t4.z + p4.z; e4[j].w = t4.w + p4.w;
        float p = e4[j].x * qv.x + e4[j].y * qv.y + e4[j].z * qv.z + e4[j].w * qv.w;
        #pragma unroll
        for (int m = 32; m >= 1; m >>= 1) p += __shfl_xor(p, m);
        if (lane == 0) s_scores[s] = p * 0.0625f;   // 1/sqrt(256)
    }
    __syncthreads();

    // ---- phase 2: softmax over S=32 (first 32 lanes of wave 0) ----
    if (tid < 32) {
        const float sc = s_scores[tid];
        float m = sc;
        #pragma unroll
        for (int k = 16; k >= 1; k >>= 1) m = fmaxf(m, __shfl_xor(m, k));
        const float e = expf(sc - m);
        float tot = e;
        #pragma unroll
        for (int k = 16; k >= 1; k >>= 1) tot += __shfl_xor(tot, k);
        s_w[tid] = e / tot;
    }
    __syncthreads();

    // ---- phase 3: per-wave partial context, pure register FMA ----
    {
        float4 c4 = {0.f, 0.f, 0.f, 0.f};
        #pragma unroll
        for (int j = 0; j < 8; ++j) {
            const float w = s_w[wave * 8 + j];
            c4.x = fmaf(w, e4[j].x, c4.x);
            c4.y = fmaf(w, e4[j].y, c4.y);
            c4.z = fmaf(w, e4[j].z, c4.z);
            c4.w = fmaf(w, e4[j].w, c4.w);
        }
        *(float4*)&s_part[wave][lane * 4] = c4;
    }
    __syncthreads();

    // ---- phase 4: cross-wave reduce -> s_ctx (thread owns d = tid) ----
    s_ctx[tid] = s_part[0][tid] + s_part[1][tid] + s_part[2][tid] + s_part[3][tid];
    __syncthreads();

    // ---- phase 5: RBF activations: thread n = tid (n < 100) ----
    float a = 0.f;
    if (tid < N_ALIVE) {
        const float4* p4 = (const float4*)(pos + (size_t)tid * D);
        const float4* c4 = (const float4*)s_ctx;
        float d2 = 0.f;
        #pragma unroll 8
        for (int dd = 0; dd < D / 4; ++dd) {
            const float4 cv = c4[dd];
            const float4 pv = p4[dd];
            const float dx = cv.x - pv.x;
            const float dy = cv.y - pv.y;
            const float dz = cv.z - pv.z;
            const float dw = cv.w - pv.w;
            d2 += dx * dx + dy * dy + dz * dz + dw * dw;
        }
        a = expf(-2.0f * d2);   // exp(-d2 / (2 * 0.5^2))
    }
    if (tid < 128) s_red[tid] = (tid < N_ALIVE) ? a : 0.f;
    __syncthreads();
    if (tid < 64) s_red[tid] += s_red[tid + 64];
    __syncthreads();
    if (tid < 64) {
        float v = s_red[tid];
        #pragma unroll
        for (int k = 32; k >= 1; k >>= 1) v += __shfl_xor(v, k);
        if (tid == 0) s_total = v;
    }
    __syncthreads();
    if (tid < K_PAD) {
        const float val = (tid < N_ALIVE) ? (a / (s_total + 1e-8f)) : 0.f;
        A[(size_t)b * K_PAD + tid] = __float2bfloat16(val);
    }
}

// ---------------------------------------------------------------------------
// Transpose/convert: Wt[v][k] = bf16(W[k][v]), zero-padded.  (unchanged)
// ---------------------------------------------------------------------------
__global__ __launch_bounds__(256) void transpose_w(
    const float* __restrict__ W,            // [N_ALIVE, V]
    __hip_bfloat16* __restrict__ Wt)        // [V_PAD, K_PAD]
{
    const int v  = blockIdx.x * 256 + threadIdx.x;
    const int k0 = blockIdx.y * 16;
    short8 p0, p1;
    #pragma unroll
    for (int kk = 0; kk < 8; ++kk) {
        const int k = k0 + kk;
        p0[kk] = f2bf((v < V && k < N_ALIVE) ? W[(size_t)k * V + v] : 0.f);
    }
    #pragma unroll
    for (int kk = 0; kk < 8; ++kk) {
        const int k = k0 + 8 + kk;
        p1[kk] = f2bf((v < V && k < N_ALIVE) ? W[(size_t)k * V + v] : 0.f);
    }
    short* dst = (short*)Wt + (size_t)v * K_PAD + k0;
    *(short8*)dst       = p0;
    *(short8*)(dst + 8) = p1;
}

#define SO_LD 260   // floats per staged row (256 + 4 pad), 16B-aligned stride

// ---------------------------------------------------------------------------
// Kernel B v3b (R22): row-owning gemm, OCCUPANCY-FIXED.
// R21 post-mortem: v3 @ 256 blocks x 4 waves = 1 wave/SIMD — the serialized
// chain (Wt load -> MFMA -> LDS -> store -> reg-copy) had nothing to hide
// under; 515.6 us.  The probe (174.5) had no dependencies, so 1 wave/SIMD
// sufficed there.  v3b: 512 threads (8 waves, 2/SIMD), wave owns 32 cols
// (2 m-tiles); ping-pong Wt buffers via unroll-2 lambda — no cur=nxt copy,
// counted vmcnt keeps stores in flight.  Same probe-validated store pattern:
// 16 sequential row streams/block, 1 KB appends.
// Predicted: gemm ~200-240 us, total ~960-1000; if >=350, revert to v2.
// ---------------------------------------------------------------------------
__global__ __launch_bounds__(512) void gemm_mfma_v3b(
    const __hip_bfloat16* __restrict__ Act,  // [B, K_PAD]
    const __hip_bfloat16* __restrict__ Wt,   // [V_PAD, K_PAD]
    float* __restrict__ out)                 // [B, V]
{
    __shared__ __align__(16) float s_out[16 * SO_LD];   // 16.6 KB block tile

    const int tid  = threadIdx.x;
    const int lane = tid & 63;
    const int wave = tid >> 6;      // 0..7, owns cols [wave*32, wave*32+32)
    const int quad = lane >> 4;
    const int l16  = lane & 15;
    const int b0   = blockIdx.x * 16;          // this block's 16 batch rows

    // ---- Act fragments: block lifetime (b-rows fixed, 16 VGPR) ----
    const short* actp = (const short*)Act + (size_t)(b0 + l16) * K_PAD + quad * 8;
    short8 bfr[4];
    #pragma unroll
    for (int ks = 0; ks < 4; ++ks) bfr[ks] = *(const short8*)(actp + ks * 32);

    // ---- Wt stream base: row (wave*32 + mt*16 + l16), col quad*8 + ks*32 ----
    const short* wtcol = (const short*)Wt + (size_t)(wave * 32 + l16) * K_PAD + quad * 8;

    short8 bufA[2][4], bufB[2][4];   // ping-pong, 2 m-tiles x 4 k-slices
    #pragma unroll
    for (int mt = 0; mt < 2; ++mt)
        #pragma unroll
        for (int ks = 0; ks < 4; ++ks)
            bufA[mt][ks] = *(const short8*)(wtcol + (size_t)(mt * 16) * K_PAD + ks * 32);

    auto body = [&](int xt, short8 (&cur)[2][4], short8 (&nxt)[2][4]) {
        const int x0 = xt * 256;
        const bool full_x = (x0 + 256 <= V);

        // prefetch next x-tile's Wt frags (clamped dup on last)
        const int xp = (xt + 1 < NXT) ? xt + 1 : xt;
        const short* wp = wtcol + (size_t)xp * 256 * K_PAD;
        #pragma unroll
        for (int mt = 0; mt < 2; ++mt)
            #pragma unroll
            for (int ks = 0; ks < 4; ++ks)
                nxt[mt][ks] = *(const short8*)(wp + (size_t)(mt * 16) * K_PAD + ks * 32);

        // MFMA: acc[reg] = C[b=l16][v = wave*32 + mt*16 + quad*4 + reg]
        #pragma unroll
        for (int mt = 0; mt < 2; ++mt) {
            float4v acc = {0.f, 0.f, 0.f, 0.f};
            #pragma unroll
            for (int ks = 0; ks < 4; ++ks)
                acc = __builtin_amdgcn_mfma_f32_16x16x32_bf16(cur[mt][ks], bfr[ks], acc, 0, 0, 0);
            *(float4v*)(s_out + l16 * SO_LD + wave * 32 + mt * 16 + quad * 4) = acc;
        }

        lds_barrier();   // ds_writes visible; global stores keep flying

        // each wave stores 2 rows: 1 KB contiguous append per row
        #pragma unroll
        for (int p = 0; p < 2; ++p) {
            const int row = wave * 2 + p;          // 0..15 (b_local)
            float* orow = out + (size_t)(b0 + row) * V + x0;
            const float* srow = s_out + row * SO_LD;
            if (full_x) {
                *(float4v*)(orow + lane * 4) = *(const float4v*)(srow + lane * 4);
            } else {
                #pragma unroll
                for (int i = 0; i < 4; ++i) {
                    const int c = lane * 4 + i;
                    if (x0 + c < V) orow[c] = srow[c];
                }
            }
        }

        lds_barrier();   // ds_reads done before next overwrite
    };

    for (int xt = 0; xt < NXT; xt += 2) {
        body(xt, bufA, bufB);
        if (xt + 1 < NXT) body(xt + 1, bufB, bufA);
    }
}

// ---------------------------------------------------------------------------
// Fallback (ws too small for Wt): fp32 VALU, TB=16 rows in VGPRs.
// ---------------------------------------------------------------------------
__global__ __launch_bounds__(256) void logits_fallback(
    const __hip_bfloat16* __restrict__ A,   // [B, K_PAD]
    const float* __restrict__ W,            // [N_ALIVE, V]
    float* __restrict__ out)                // [B, V]
{
    const int v  = blockIdx.x * 256 + threadIdx.x;
    const int b0 = blockIdx.y * 16;
    const bool valid = (v < V);

    float acc[16];
    #pragma unroll
    for (int i = 0; i < 16; ++i) acc[i] = 0.f;

    for (int k = 0; k < N_ALIVE; ++k) {
        const float w = valid ? W[(size_t)k * V + v] : 0.f;
        #pragma unroll
        for (int i = 0; i < 16; ++i) {
            const float a = __bfloat162float(A[(size_t)(b0 + i) * K_PAD + k]);
            acc[i] = fmaf(a, w, acc[i]);
        }
    }
    if (valid) {
        #pragma unroll
        for (int i = 0; i < 16; ++i)
            out[(size_t)(b0 + i) * V + v] = acc[i];
    }
}

// ---------------------------------------------------------------------------
extern "C" void kernel_launch(void* const* d_in, const int* in_sizes, int n_in,
                              void* d_out, int out_size, void* d_ws, size_t ws_size,
                              hipStream_t stream) {
    const int*   token_ids = (const int*)d_in[0];
    const float* te        = (const float*)d_in[1];
    const float* pe        = (const float*)d_in[2];
    const float* q         = (const float*)d_in[3];
    const float* pos       = (const float*)d_in[4];
    const float* W         = (const float*)d_in[5];
    float*       out       = (float*)d_out;

    __hip_bfloat16* Abf = (__hip_bfloat16*)d_ws;                  // 1 MiB
    const size_t offW   = (size_t)B * K_PAD * sizeof(__hip_bfloat16);
    __hip_bfloat16* Wt  = (__hip_bfloat16*)((char*)d_ws + offW);  // ~12.9 MB
    const size_t need   = offW + (size_t)V_PAD * K_PAD * sizeof(__hip_bfloat16);

    ctx_act_kernel<<<dim3(B), dim3(256), 0, stream>>>(token_ids, te, pe, q, pos, Abf);

    if (ws_size >= need) {
        transpose_w<<<dim3(V_PAD / 256, 8), dim3(256), 0, stream>>>(W, Wt);
        gemm_mfma_v3b<<<dim3(B / 16), dim3(512), 0, stream>>>(Abf, Wt, out);
    } else {
        logits_fallback<<<dim3((V + 255) / 256, B / 16), dim3(256), 0, stream>>>(Abf, W, out);
    }
}

// Round 14
// 1027.343 us; speedup vs baseline: 1.2432x; 1.2239x over previous
//
#include <hip/hip_runtime.h>
#include <hip/hip_bf16.h>
#include <math.h>

#define B 4096
#define S 32
#define D 256
#define V 50257
#define N_ALIVE 100
#define K_PAD 128          // K=100 zero-padded to 128 (4 x mfma K=32)
#define V_PAD 50432        // 197 * 256

typedef __attribute__((ext_vector_type(8))) short short8;   // 8 bf16 (4 VGPRs)
typedef __attribute__((ext_vector_type(4))) float float4v;  // 4 fp32 (native vec)

__device__ __forceinline__ short f2bf(float f) {
    __hip_bfloat16 h = __float2bfloat16(f);
    return *reinterpret_cast<short*>(&h);
}

// LDS-only barrier: orders ds_write->ds_read across waves WITHOUT draining
// outstanding global stores (unlike __syncthreads, which emits vmcnt(0)).
__device__ __forceinline__ void lds_barrier() {
    asm volatile("s_waitcnt lgkmcnt(0)" ::: "memory");
    __builtin_amdgcn_s_barrier();
}

// ---------------------------------------------------------------------------
// Kernel A v3 (unchanged).  Measured R14: 54 us.
// ---------------------------------------------------------------------------
__global__ __launch_bounds__(256) void ctx_act_kernel(
    const int*   __restrict__ token_ids,   // [B,S]
    const float* __restrict__ te,          // [V,D]
    const float* __restrict__ pe,          // [S,D]
    const float* __restrict__ q,           // [D]
    const float* __restrict__ pos,         // [N,D]
    __hip_bfloat16* __restrict__ A)        // [B, K_PAD]
{
    __shared__ int   s_ids[S];
    __shared__ float s_scores[S];
    __shared__ float s_w[S];
    __shared__ __align__(16) float s_part[4][D];   // 4 KB per-wave partials
    __shared__ __align__(16) float s_ctx[D];
    __shared__ float s_red[128];
    __shared__ float s_total;

    const int b    = blockIdx.x;
    const int tid  = threadIdx.x;
    const int lane = tid & 63;
    const int wave = tid >> 6;

    if (tid < S) s_ids[tid] = token_ids[b * S + tid];
    __syncthreads();

    // ---- phase 1: load embeds (kept in regs) + attention scores ----
    const float4 qv = *(const float4*)(q + lane * 4);
    float4 e4[8];
    #pragma unroll
    for (int j = 0; j < 8; ++j) {
        const int s = wave * 8 + j;
        const float4 t4 = *(const float4*)(te + (size_t)s_ids[s] * D + lane * 4);
        const float4 p4 = *(const float4*)(pe + (size_t)s * D + lane * 4);
        e4[j].x = t4.x + p4.x; e4[j].y = t4.y + p4.y;
        e4[j].z = t4.z + p4.z; e4[j].w = t4.w + p4.w;
        float p = e4[j].x * qv.x + e4[j].y * qv.y + e4[j].z * qv.z + e4[j].w * qv.w;
        #pragma unroll
        for (int m = 32; m >= 1; m >>= 1) p += __shfl_xor(p, m);
        if (lane == 0) s_scores[s] = p * 0.0625f;   // 1/sqrt(256)
    }
    __syncthreads();

    // ---- phase 2: softmax over S=32 (first 32 lanes of wave 0) ----
    if (tid < 32) {
        const float sc = s_scores[tid];
        float m = sc;
        #pragma unroll
        for (int k = 16; k >= 1; k >>= 1) m = fmaxf(m, __shfl_xor(m, k));
        const float e = expf(sc - m);
        float tot = e;
        #pragma unroll
        for (int k = 16; k >= 1; k >>= 1) tot += __shfl_xor(tot, k);
        s_w[tid] = e / tot;
    }
    __syncthreads();

    // ---- phase 3: per-wave partial context, pure register FMA ----
    {
        float4 c4 = {0.f, 0.f, 0.f, 0.f};
        #pragma unroll
        for (int j = 0; j < 8; ++j) {
            const float w = s_w[wave * 8 + j];
            c4.x = fmaf(w, e4[j].x, c4.x);
            c4.y = fmaf(w, e4[j].y, c4.y);
            c4.z = fmaf(w, e4[j].z, c4.z);
            c4.w = fmaf(w, e4[j].w, c4.w);
        }
        *(float4*)&s_part[wave][lane * 4] = c4;
    }
    __syncthreads();

    // ---- phase 4: cross-wave reduce -> s_ctx (thread owns d = tid) ----
    s_ctx[tid] = s_part[0][tid] + s_part[1][tid] + s_part[2][tid] + s_part[3][tid];
    __syncthreads();

    // ---- phase 5: RBF activations: thread n = tid (n < 100) ----
    float a = 0.f;
    if (tid < N_ALIVE) {
        const float4* p4 = (const float4*)(pos + (size_t)tid * D);
        const float4* c4 = (const float4*)s_ctx;
        float d2 = 0.f;
        #pragma unroll 8
        for (int dd = 0; dd < D / 4; ++dd) {
            const float4 cv = c4[dd];
            const float4 pv = p4[dd];
            const float dx = cv.x - pv.x;
            const float dy = cv.y - pv.y;
            const float dz = cv.z - pv.z;
            const float dw = cv.w - pv.w;
            d2 += dx * dx + dy * dy + dz * dz + dw * dw;
        }
        a = expf(-2.0f * d2);   // exp(-d2 / (2 * 0.5^2))
    }
    if (tid < 128) s_red[tid] = (tid < N_ALIVE) ? a : 0.f;
    __syncthreads();
    if (tid < 64) s_red[tid] += s_red[tid + 64];
    __syncthreads();
    if (tid < 64) {
        float v = s_red[tid];
        #pragma unroll
        for (int k = 32; k >= 1; k >>= 1) v += __shfl_xor(v, k);
        if (tid == 0) s_total = v;
    }
    __syncthreads();
    if (tid < K_PAD) {
        const float val = (tid < N_ALIVE) ? (a / (s_total + 1e-8f)) : 0.f;
        A[(size_t)b * K_PAD + tid] = __float2bfloat16(val);
    }
}

// ---------------------------------------------------------------------------
// Transpose/convert: Wt[v][k] = bf16(W[k][v]), zero-padded.  (unchanged)
// ---------------------------------------------------------------------------
__global__ __launch_bounds__(256) void transpose_w(
    const float* __restrict__ W,            // [N_ALIVE, V]
    __hip_bfloat16* __restrict__ Wt)        // [V_PAD, K_PAD]
{
    const int v  = blockIdx.x * 256 + threadIdx.x;
    const int k0 = blockIdx.y * 16;
    short8 p0, p1;
    #pragma unroll
    for (int kk = 0; kk < 8; ++kk) {
        const int k = k0 + kk;
        p0[kk] = f2bf((v < V && k < N_ALIVE) ? W[(size_t)k * V + v] : 0.f);
    }
    #pragma unroll
    for (int kk = 0; kk < 8; ++kk) {
        const int k = k0 + 8 + kk;
        p1[kk] = f2bf((v < V && k < N_ALIVE) ? W[(size_t)k * V + v] : 0.f);
    }
    short* dst = (short*)Wt + (size_t)v * K_PAD + k0;
    *(short8*)dst       = p0;
    *(short8*)(dst + 8) = p1;
}

// ---------------------------------------------------------------------------
// Kernel B (R23): v2 with NT2=32 — final amortization step.
// R21/R22 row-owning redesigns REVERTED (structural flaw: 256 blocks x full
// 12.9 MB Wt re-read = 3.3 GB L3 traffic, ~+240 us both).  v2 structure is
// at its store-pattern floor (R18 probe: 244.7 of its 256.7 is pure store
// drain).  NT 8->16 measured -32 us (prologue amortization); 16->32 is the
// same mechanism, expected -5..-15 us, else R16 stands as final.
// ---------------------------------------------------------------------------
#define SO_LD 260   // floats per staged row (256 + 4 pad), 16B-aligned stride
#define NT2 32      // 32 n-tiles of 16 b-rows = 512 batch rows per block

__global__ __launch_bounds__(256) void gemm_mfma_v2(
    const __hip_bfloat16* __restrict__ Act,  // [B, K_PAD]
    const __hip_bfloat16* __restrict__ Wt,   // [V_PAD, K_PAD]
    float* __restrict__ out)                 // [B, V]
{
    __shared__ __align__(16) float s_out[16 * SO_LD];   // 16.6 KB block tile

    const int tid  = threadIdx.x;
    const int lane = tid & 63;
    const int wave = tid >> 6;
    const int quad = lane >> 4;
    const int l16  = lane & 15;
    const int b0   = blockIdx.y * (NT2 * 16);  // 512 batch rows per block
    const int x0   = blockIdx.x * 256;
    const int wx0  = x0 + wave * 64;           // this wave's 64 v-cols

    // ---- hoist Wt fragments for all 4 m-tiles (block lifetime, 64 VGPR) ----
    const short* wtbase = (const short*)Wt + (size_t)(wx0 + l16) * K_PAD + quad * 8;
    short8 wf[4][4];
    #pragma unroll
    for (int mt = 0; mt < 4; ++mt) {
        const short* ap = wtbase + (size_t)(mt * 16) * K_PAD;
        #pragma unroll
        for (int ks = 0; ks < 4; ++ks) wf[mt][ks] = *(const short8*)(ap + ks * 32);
    }

    const short* actbase = (const short*)Act + (size_t)(b0 + l16) * K_PAD + quad * 8;
    short8 cur[4], nxt[4];
    #pragma unroll
    for (int ks = 0; ks < 4; ++ks) cur[ks] = *(const short8*)(actbase + ks * 32);

    #pragma unroll 4
    for (int n = 0; n < NT2; ++n) {
        // prefetch next iter's Act fragments (clamped dup on last iter)
        const int np = (n + 1 < NT2) ? n + 1 : n;
        const short* anp = actbase + (size_t)(np * 16) * K_PAD;
        #pragma unroll
        for (int ks = 0; ks < 4; ++ks) nxt[ks] = *(const short8*)(anp + ks * 32);

        // acc[reg] = C[b_local = l16][v_local = wave*64 + mt*16 + quad*4 + reg]
        #pragma unroll
        for (int mt = 0; mt < 4; ++mt) {
            float4v acc = {0.f, 0.f, 0.f, 0.f};
            #pragma unroll
            for (int ks = 0; ks < 4; ++ks)
                acc = __builtin_amdgcn_mfma_f32_16x16x32_bf16(wf[mt][ks], cur[ks], acc, 0, 0, 0);
            *(float4v*)(s_out + l16 * SO_LD + wave * 64 + mt * 16 + quad * 4) = acc;
        }

        lds_barrier();   // ds_writes visible; global stores keep flying

        #pragma unroll
        for (int p = 0; p < 4; ++p) {
            const int row   = wave * 4 + p;            // 0..15 (b_local)
            const int vglob = x0 + lane * 4;
            const float4v val = *(const float4v*)(s_out + row * SO_LD + lane * 4);
            float* orow = out + (size_t)(b0 + n * 16 + row) * V + vglob;
            if (vglob + 4 <= V) {
                *(float4v*)orow = val;
            } else {
                if (vglob + 0 < V) orow[0] = val[0];
                if (vglob + 1 < V) orow[1] = val[1];
                if (vglob + 2 < V) orow[2] = val[2];
                if (vglob + 3 < V) orow[3] = val[3];
            }
        }

        lds_barrier();   // ds_reads done before next overwrite

        #pragma unroll
        for (int ks = 0; ks < 4; ++ks) cur[ks] = nxt[ks];
    }
}

// ---------------------------------------------------------------------------
// Fallback (ws too small for Wt): fp32 VALU, TB=16 rows in VGPRs.
// ---------------------------------------------------------------------------
__global__ __launch_bounds__(256) void logits_fallback(
    const __hip_bfloat16* __restrict__ A,   // [B, K_PAD]
    const float* __restrict__ W,            // [N_ALIVE, V]
    float* __restrict__ out)                // [B, V]
{
    const int v  = blockIdx.x * 256 + threadIdx.x;
    const int b0 = blockIdx.y * 16;
    const bool valid = (v < V);

    float acc[16];
    #pragma unroll
    for (int i = 0; i < 16; ++i) acc[i] = 0.f;

    for (int k = 0; k < N_ALIVE; ++k) {
        const float w = valid ? W[(size_t)k * V + v] : 0.f;
        #pragma unroll
        for (int i = 0; i < 16; ++i) {
            const float a = __bfloat162float(A[(size_t)(b0 + i) * K_PAD + k]);
            acc[i] = fmaf(a, w, acc[i]);
        }
    }
    if (valid) {
        #pragma unroll
        for (int i = 0; i < 16; ++i)
            out[(size_t)(b0 + i) * V + v] = acc[i];
    }
}

// ---------------------------------------------------------------------------
extern "C" void kernel_launch(void* const* d_in, const int* in_sizes, int n_in,
                              void* d_out, int out_size, void* d_ws, size_t ws_size,
                              hipStream_t stream) {
    const int*   token_ids = (const int*)d_in[0];
    const float* te        = (const float*)d_in[1];
    const float* pe        = (const float*)d_in[2];
    const float* q         = (const float*)d_in[3];
    const float* pos       = (const float*)d_in[4];
    const float* W         = (const float*)d_in[5];
    float*       out       = (float*)d_out;

    __hip_bfloat16* Abf = (__hip_bfloat16*)d_ws;                  // 1 MiB
    const size_t offW   = (size_t)B * K_PAD * sizeof(__hip_bfloat16);
    __hip_bfloat16* Wt  = (__hip_bfloat16*)((char*)d_ws + offW);  // ~12.9 MB
    const size_t need   = offW + (size_t)V_PAD * K_PAD * sizeof(__hip_bfloat16);

    ctx_act_kernel<<<dim3(B), dim3(256), 0, stream>>>(token_ids, te, pe, q, pos, Abf);

    if (ws_size >= need) {
        transpose_w<<<dim3(V_PAD / 256, 8), dim3(256), 0, stream>>>(W, Wt);
        gemm_mfma_v2<<<dim3(V_PAD / 256, B / (NT2 * 16)), dim3(256), 0, stream>>>(Abf, Wt, out);
    } else {
        logits_fallback<<<dim3((V + 255) / 256, B / 16), dim3(256), 0, stream>>>(Abf, W, out);
    }
}

// Round 15
// 1019.123 us; speedup vs baseline: 1.2532x; 1.0081x over previous
//
#include <hip/hip_runtime.h>
#include <hip/hip_bf16.h>
#include <math.h>

#define B 4096
#define S 32
#define D 256
#define V 50257
#define N_ALIVE 100
#define K_PAD 128          // K=100 zero-padded to 128 (4 x mfma K=32)
#define V_PAD 50432        // 197 * 256

typedef __attribute__((ext_vector_type(8))) short short8;   // 8 bf16 (4 VGPRs)
typedef __attribute__((ext_vector_type(4))) float float4v;  // 4 fp32 (native vec)

__device__ __forceinline__ short f2bf(float f) {
    __hip_bfloat16 h = __float2bfloat16(f);
    return *reinterpret_cast<short*>(&h);
}

// LDS-only barrier: orders ds_write->ds_read across waves WITHOUT draining
// outstanding global stores (unlike __syncthreads, which emits vmcnt(0)).
__device__ __forceinline__ void lds_barrier() {
    asm volatile("s_waitcnt lgkmcnt(0)" ::: "memory");
    __builtin_amdgcn_s_barrier();
}

// ---------------------------------------------------------------------------
// Kernel A v3 (final).  Measured R14: 54 us.
// ---------------------------------------------------------------------------
__global__ __launch_bounds__(256) void ctx_act_kernel(
    const int*   __restrict__ token_ids,   // [B,S]
    const float* __restrict__ te,          // [V,D]
    const float* __restrict__ pe,          // [S,D]
    const float* __restrict__ q,           // [D]
    const float* __restrict__ pos,         // [N,D]
    __hip_bfloat16* __restrict__ A)        // [B, K_PAD]
{
    __shared__ int   s_ids[S];
    __shared__ float s_scores[S];
    __shared__ float s_w[S];
    __shared__ __align__(16) float s_part[4][D];   // 4 KB per-wave partials
    __shared__ __align__(16) float s_ctx[D];
    __shared__ float s_red[128];
    __shared__ float s_total;

    const int b    = blockIdx.x;
    const int tid  = threadIdx.x;
    const int lane = tid & 63;
    const int wave = tid >> 6;

    if (tid < S) s_ids[tid] = token_ids[b * S + tid];
    __syncthreads();

    // ---- phase 1: load embeds (kept in regs) + attention scores ----
    const float4 qv = *(const float4*)(q + lane * 4);
    float4 e4[8];
    #pragma unroll
    for (int j = 0; j < 8; ++j) {
        const int s = wave * 8 + j;
        const float4 t4 = *(const float4*)(te + (size_t)s_ids[s] * D + lane * 4);
        const float4 p4 = *(const float4*)(pe + (size_t)s * D + lane * 4);
        e4[j].x = t4.x + p4.x; e4[j].y = t4.y + p4.y;
        e4[j].z = t4.z + p4.z; e4[j].w = t4.w + p4.w;
        float p = e4[j].x * qv.x + e4[j].y * qv.y + e4[j].z * qv.z + e4[j].w * qv.w;
        #pragma unroll
        for (int m = 32; m >= 1; m >>= 1) p += __shfl_xor(p, m);
        if (lane == 0) s_scores[s] = p * 0.0625f;   // 1/sqrt(256)
    }
    __syncthreads();

    // ---- phase 2: softmax over S=32 (first 32 lanes of wave 0) ----
    if (tid < 32) {
        const float sc = s_scores[tid];
        float m = sc;
        #pragma unroll
        for (int k = 16; k >= 1; k >>= 1) m = fmaxf(m, __shfl_xor(m, k));
        const float e = expf(sc - m);
        float tot = e;
        #pragma unroll
        for (int k = 16; k >= 1; k >>= 1) tot += __shfl_xor(tot, k);
        s_w[tid] = e / tot;
    }
    __syncthreads();

    // ---- phase 3: per-wave partial context, pure register FMA ----
    {
        float4 c4 = {0.f, 0.f, 0.f, 0.f};
        #pragma unroll
        for (int j = 0; j < 8; ++j) {
            const float w = s_w[wave * 8 + j];
            c4.x = fmaf(w, e4[j].x, c4.x);
            c4.y = fmaf(w, e4[j].y, c4.y);
            c4.z = fmaf(w, e4[j].z, c4.z);
            c4.w = fmaf(w, e4[j].w, c4.w);
        }
        *(float4*)&s_part[wave][lane * 4] = c4;
    }
    __syncthreads();

    // ---- phase 4: cross-wave reduce -> s_ctx (thread owns d = tid) ----
    s_ctx[tid] = s_part[0][tid] + s_part[1][tid] + s_part[2][tid] + s_part[3][tid];
    __syncthreads();

    // ---- phase 5: RBF activations: thread n = tid (n < 100) ----
    float a = 0.f;
    if (tid < N_ALIVE) {
        const float4* p4 = (const float4*)(pos + (size_t)tid * D);
        const float4* c4 = (const float4*)s_ctx;
        float d2 = 0.f;
        #pragma unroll 8
        for (int dd = 0; dd < D / 4; ++dd) {
            const float4 cv = c4[dd];
            const float4 pv = p4[dd];
            const float dx = cv.x - pv.x;
            const float dy = cv.y - pv.y;
            const float dz = cv.z - pv.z;
            const float dw = cv.w - pv.w;
            d2 += dx * dx + dy * dy + dz * dz + dw * dw;
        }
        a = expf(-2.0f * d2);   // exp(-d2 / (2 * 0.5^2))
    }
    if (tid < 128) s_red[tid] = (tid < N_ALIVE) ? a : 0.f;
    __syncthreads();
    if (tid < 64) s_red[tid] += s_red[tid + 64];
    __syncthreads();
    if (tid < 64) {
        float v = s_red[tid];
        #pragma unroll
        for (int k = 32; k >= 1; k >>= 1) v += __shfl_xor(v, k);
        if (tid == 0) s_total = v;
    }
    __syncthreads();
    if (tid < K_PAD) {
        const float val = (tid < N_ALIVE) ? (a / (s_total + 1e-8f)) : 0.f;
        A[(size_t)b * K_PAD + tid] = __float2bfloat16(val);
    }
}

// ---------------------------------------------------------------------------
// Transpose/convert: Wt[v][k] = bf16(W[k][v]), zero-padded.  (final)
// ---------------------------------------------------------------------------
__global__ __launch_bounds__(256) void transpose_w(
    const float* __restrict__ W,            // [N_ALIVE, V]
    __hip_bfloat16* __restrict__ Wt)        // [V_PAD, K_PAD]
{
    const int v  = blockIdx.x * 256 + threadIdx.x;
    const int k0 = blockIdx.y * 16;
    short8 p0, p1;
    #pragma unroll
    for (int kk = 0; kk < 8; ++kk) {
        const int k = k0 + kk;
        p0[kk] = f2bf((v < V && k < N_ALIVE) ? W[(size_t)k * V + v] : 0.f);
    }
    #pragma unroll
    for (int kk = 0; kk < 8; ++kk) {
        const int k = k0 + 8 + kk;
        p1[kk] = f2bf((v < V && k < N_ALIVE) ? W[(size_t)k * V + v] : 0.f);
    }
    short* dst = (short*)Wt + (size_t)v * K_PAD + k0;
    *(short8*)dst       = p0;
    *(short8*)(dst + 8) = p1;
}

// ---------------------------------------------------------------------------
// Kernel B FINAL = R16 exactly (best measured: gemm 256.7 us, total 1018.3).
//   NT2=16 (256 rows/block, 3152 blocks): optimum of the family —
//   NT=8: 288.6, NT=16: 256.7, NT=32: ~266 (R23).
//   Register Act prefetch (next n-tile issued before MFMA+stores).
//   Staged 1-KB contiguous stores via LDS; LDS-only barriers (no vmcnt
//   drain — stores stay in flight across iterations).
// Ledger: fixed harness window 762 (fill 520 + ctx 54 + tr 10 + gaps 180)
// + stores-at-pattern-floor 245 (R18 probe) + compute 12 = 1019 ≈ measured.
// Falsified alternatives: NT-stores(+125), swizzle(+20), align-peel(+11),
// vmcnt-drain(0), NT=32(+9), row-owning x2 (+240: 256-block Wt re-read).
// ---------------------------------------------------------------------------
#define SO_LD 260   // floats per staged row (256 + 4 pad), 16B-aligned stride
#define NT2 16      // 16 n-tiles of 16 b-rows = 256 batch rows per block

__global__ __launch_bounds__(256) void gemm_mfma_v2(
    const __hip_bfloat16* __restrict__ Act,  // [B, K_PAD]
    const __hip_bfloat16* __restrict__ Wt,   // [V_PAD, K_PAD]
    float* __restrict__ out)                 // [B, V]
{
    __shared__ __align__(16) float s_out[16 * SO_LD];   // 16.6 KB block tile

    const int tid  = threadIdx.x;
    const int lane = tid & 63;
    const int wave = tid >> 6;
    const int quad = lane >> 4;
    const int l16  = lane & 15;
    const int b0   = blockIdx.y * (NT2 * 16);  // 256 batch rows per block
    const int x0   = blockIdx.x * 256;
    const int wx0  = x0 + wave * 64;           // this wave's 64 v-cols

    // ---- hoist Wt fragments for all 4 m-tiles (block lifetime, 64 VGPR) ----
    const short* wtbase = (const short*)Wt + (size_t)(wx0 + l16) * K_PAD + quad * 8;
    short8 wf[4][4];
    #pragma unroll
    for (int mt = 0; mt < 4; ++mt) {
        const short* ap = wtbase + (size_t)(mt * 16) * K_PAD;
        #pragma unroll
        for (int ks = 0; ks < 4; ++ks) wf[mt][ks] = *(const short8*)(ap + ks * 32);
    }

    const short* actbase = (const short*)Act + (size_t)(b0 + l16) * K_PAD + quad * 8;
    short8 cur[4], nxt[4];
    #pragma unroll
    for (int ks = 0; ks < 4; ++ks) cur[ks] = *(const short8*)(actbase + ks * 32);

    #pragma unroll 4
    for (int n = 0; n < NT2; ++n) {
        // prefetch next iter's Act fragments (clamped dup on last iter)
        const int np = (n + 1 < NT2) ? n + 1 : n;
        const short* anp = actbase + (size_t)(np * 16) * K_PAD;
        #pragma unroll
        for (int ks = 0; ks < 4; ++ks) nxt[ks] = *(const short8*)(anp + ks * 32);

        // acc[reg] = C[b_local = l16][v_local = wave*64 + mt*16 + quad*4 + reg]
        #pragma unroll
        for (int mt = 0; mt < 4; ++mt) {
            float4v acc = {0.f, 0.f, 0.f, 0.f};
            #pragma unroll
            for (int ks = 0; ks < 4; ++ks)
                acc = __builtin_amdgcn_mfma_f32_16x16x32_bf16(wf[mt][ks], cur[ks], acc, 0, 0, 0);
            *(float4v*)(s_out + l16 * SO_LD + wave * 64 + mt * 16 + quad * 4) = acc;
        }

        lds_barrier();   // ds_writes visible; global stores keep flying

        #pragma unroll
        for (int p = 0; p < 4; ++p) {
            const int row   = wave * 4 + p;            // 0..15 (b_local)
            const int vglob = x0 + lane * 4;
            const float4v val = *(const float4v*)(s_out + row * SO_LD + lane * 4);
            float* orow = out + (size_t)(b0 + n * 16 + row) * V + vglob;
            if (vglob + 4 <= V) {
                *(float4v*)orow = val;
            } else {
                if (vglob + 0 < V) orow[0] = val[0];
                if (vglob + 1 < V) orow[1] = val[1];
                if (vglob + 2 < V) orow[2] = val[2];
                if (vglob + 3 < V) orow[3] = val[3];
            }
        }

        lds_barrier();   // ds_reads done before next overwrite

        #pragma unroll
        for (int ks = 0; ks < 4; ++ks) cur[ks] = nxt[ks];
    }
}

// ---------------------------------------------------------------------------
// Fallback (ws too small for Wt): fp32 VALU, TB=16 rows in VGPRs.
// ---------------------------------------------------------------------------
__global__ __launch_bounds__(256) void logits_fallback(
    const __hip_bfloat16* __restrict__ A,   // [B, K_PAD]
    const float* __restrict__ W,            // [N_ALIVE, V]
    float* __restrict__ out)                // [B, V]
{
    const int v  = blockIdx.x * 256 + threadIdx.x;
    const int b0 = blockIdx.y * 16;
    const bool valid = (v < V);

    float acc[16];
    #pragma unroll
    for (int i = 0; i < 16; ++i) acc[i] = 0.f;

    for (int k = 0; k < N_ALIVE; ++k) {
        const float w = valid ? W[(size_t)k * V + v] : 0.f;
        #pragma unroll
        for (int i = 0; i < 16; ++i) {
            const float a = __bfloat162float(A[(size_t)(b0 + i) * K_PAD + k]);
            acc[i] = fmaf(a, w, acc[i]);
        }
    }
    if (valid) {
        #pragma unroll
        for (int i = 0; i < 16; ++i)
            out[(size_t)(b0 + i) * V + v] = acc[i];
    }
}

// ---------------------------------------------------------------------------
extern "C" void kernel_launch(void* const* d_in, const int* in_sizes, int n_in,
                              void* d_out, int out_size, void* d_ws, size_t ws_size,
                              hipStream_t stream) {
    const int*   token_ids = (const int*)d_in[0];
    const float* te        = (const float*)d_in[1];
    const float* pe        = (const float*)d_in[2];
    const float* q         = (const float*)d_in[3];
    const float* pos       = (const float*)d_in[4];
    const float* W         = (const float*)d_in[5];
    float*       out       = (float*)d_out;

    __hip_bfloat16* Abf = (__hip_bfloat16*)d_ws;                  // 1 MiB
    const size_t offW   = (size_t)B * K_PAD * sizeof(__hip_bfloat16);
    __hip_bfloat16* Wt  = (__hip_bfloat16*)((char*)d_ws + offW);  // ~12.9 MB
    const size_t need   = offW + (size_t)V_PAD * K_PAD * sizeof(__hip_bfloat16);

    ctx_act_kernel<<<dim3(B), dim3(256), 0, stream>>>(token_ids, te, pe, q, pos, Abf);

    if (ws_size >= need) {
        transpose_w<<<dim3(V_PAD / 256, 8), dim3(256), 0, stream>>>(W, Wt);
        gemm_mfma_v2<<<dim3(V_PAD / 256, B / (NT2 * 16)), dim3(256), 0, stream>>>(Abf, Wt, out);
    } else {
        logits_fallback<<<dim3((V + 255) / 256, B / 16), dim3(256), 0, stream>>>(Abf, W, out);
    }
}